// Round 2
// baseline (179.521 us; speedup 1.0000x reference)
//
#include <hip/hip_runtime.h>

// BERT lattice embedding: ragged segment mean-pool.
// hidden: [B,S,H] f32, word_ids: [B,S] i32 (non-decreasing per sample),
// out: [B,T,H] f32 with out[b,t,:] = mean over the contiguous run of s with
// word_ids[b,s]==t (zeros if the run is empty).
//
// R1 design: one 256-thread block per (b, 16 consecutive t).
//  - word_ids row (512 ints) staged to LDS once per block.
//  - Run boundaries found by a parallel neighbor-compare scatter (no binary
//    search; kills the 18-deep dependent-load chain that made R0 latency-bound).
//  - Each of the 4 waves pools 4 output rows: lane i owns float4 elements
//    {i, i+64, i+128} of the 768-float row. Fully coalesced 16B/lane.

#define BB 64
#define SS 512
#define HH 768
#define TT 400
#define TCHUNK 16                  // t-values per block; 400/16 = 25 chunks
#define NCHUNK (TT / TCHUNK)

__global__ __launch_bounds__(256) void bert_lattice_pool_kernel(
    const float* __restrict__ hidden,
    const int* __restrict__ word_ids,
    float* __restrict__ out)
{
    __shared__ int wid[SS];
    __shared__ int sstart[TCHUNK];
    __shared__ int send[TCHUNK];

    const int blk = blockIdx.x;             // b * NCHUNK + chunk
    const int b   = blk / NCHUNK;
    const int t0  = (blk - b * NCHUNK) * TCHUNK;

    const int tid = threadIdx.x;

    // Stage word_ids row into LDS (2 ints/thread, vectorized) and init tables.
    {
        const int2* src = reinterpret_cast<const int2*>(word_ids + b * SS);
        reinterpret_cast<int2*>(wid)[tid] = src[tid];
    }
    if (tid < TCHUNK) { sstart[tid] = 0; send[tid] = 0; }
    __syncthreads();

    // Parallel boundary scatter: each run of word w has exactly one first-s
    // and one last-s; distinct runs -> distinct rel slots, so no races.
    #pragma unroll
    for (int k = 0; k < SS / 256; ++k) {
        const int s   = tid + k * 256;
        const int w   = wid[s];
        const int rel = w - t0;
        if (rel >= 0 && rel < TCHUNK) {
            if (s == 0      || wid[s - 1] != w) sstart[rel] = s;
            if (s == SS - 1 || wid[s + 1] != w) send[rel]   = s + 1;
        }
    }
    __syncthreads();

    const int wave = tid >> 6;
    const int lane = tid & 63;

    #pragma unroll
    for (int i = 0; i < TCHUNK / 4; ++i) {
        const int trel  = wave * (TCHUNK / 4) + i;
        const int start = sstart[trel];      // wave-uniform LDS broadcast
        const int end   = send[trel];
        const int count = end - start;

        float4 acc0 = make_float4(0.f, 0.f, 0.f, 0.f);
        float4 acc1 = make_float4(0.f, 0.f, 0.f, 0.f);
        float4 acc2 = make_float4(0.f, 0.f, 0.f, 0.f);

        for (int s = start; s < end; ++s) {
            const float4* p =
                reinterpret_cast<const float4*>(hidden + ((size_t)b * SS + s) * HH);
            float4 v0 = p[lane];
            float4 v1 = p[lane + 64];
            float4 v2 = p[lane + 128];
            acc0.x += v0.x; acc0.y += v0.y; acc0.z += v0.z; acc0.w += v0.w;
            acc1.x += v1.x; acc1.y += v1.y; acc1.z += v1.z; acc1.w += v1.w;
            acc2.x += v2.x; acc2.y += v2.y; acc2.z += v2.z; acc2.w += v2.w;
        }

        const float inv = 1.0f / (float)(count > 0 ? count : 1);

        float4* o = reinterpret_cast<float4*>(out + ((size_t)b * TT + t0 + trel) * HH);
        o[lane]       = make_float4(acc0.x * inv, acc0.y * inv, acc0.z * inv, acc0.w * inv);
        o[lane + 64]  = make_float4(acc1.x * inv, acc1.y * inv, acc1.z * inv, acc1.w * inv);
        o[lane + 128] = make_float4(acc2.x * inv, acc2.y * inv, acc2.z * inv, acc2.w * inv);
    }
}

extern "C" void kernel_launch(void* const* d_in, const int* in_sizes, int n_in,
                              void* d_out, int out_size, void* d_ws, size_t ws_size,
                              hipStream_t stream) {
    (void)in_sizes; (void)n_in; (void)d_ws; (void)ws_size; (void)out_size;
    const float* hidden   = (const float*)d_in[0];
    const int*   word_ids = (const int*)d_in[1];
    float*       out      = (float*)d_out;

    dim3 grid(BB * NCHUNK);   // 64 * 25 = 1600 blocks
    dim3 block(256);
    bert_lattice_pool_kernel<<<grid, block, 0, stream>>>(hidden, word_ids, out);
}